// Round 10
// baseline (71.488 us; speedup 1.0000x reference)
//
#include <hip/hip_runtime.h>
#include <math.h>

#define WL   140
#define OFC  118
#define TDN  21
#define COUT 10
#define KS   9
#define IW_SZ (OFC * OFC)       // 13924

// ws layout (floats)
#define PROJ_STRIDE 6848
#define KP_OFF      1888
#define WS_ATT_A    13696
#define WS_ATT_B    13824
#define WS_FEATS    13952
#define WS_FLAGS    14080

// flag slots (stride 16 ints): qk proj blocks 2..19 -> slot blk-2 (0..17);
// attA=18, attB=19; feats br -> 20+br (20..23). 24 slots.
#define MAGIC 0x1F2E3D4C
#define NSLOTS 24

struct Params {
    const float *x;
    const float *tdA_in_w, *tdA_in_b, *tdA_out_w, *tdA_out_b;
    const float *tdB_in_w, *tdB_in_b, *tdB_out_w, *tdB_out_b;
    const float *cm_in_w, *cm_in_b, *cm_out_w, *cm_out_b;
    const float *projA_w, *projB_w, *conv_w, *conv_b;
    const float *fc1_w, *fc1_b, *fc2_w, *fc2_b;
    float *ws, *out;
};

struct MnSm {                     // blocks 0,1: v-path + phase2 (+ head on 0)
    float wout[OFC][122];         // W_out rows, padded
    float vp [TDN][122];          // V projection (in-LDS only)
    float vpw[TDN][122];          // vp @ W_out^T
    float qpp[16][122];
    float kpp[TDN][122];
    float eeg[16][122];
    float attn[16][22];
    float acs[22];
    float colsum[120];
    float Ssum[16];
    float bout[120];
    float fc1w[1600], fc1b[40], fc2w[80], fc2b[2];
    float hf[40], hh[40];
    int   sel;
};

struct BrSm {                     // blocks 20..23
    float arow[120];
    float pv[16];
    float eeg_s[16][OFC];
    float w_inT[16][48];
    float b_in[48];
    float tv[3][16];
    float w_out[16][16];
    float b_out[16];
    float cw[COUT * 16 * KS];
    float cb[COUT];
    float kpS[OFC][17];
    float vpS[OFC][17];
    float u[120], v2[120];
    float part_m[4][128];
    float part_l[4][128];
    float part_acc[4][OFC][17];
    float o2[OFC][17];
    float qpS[OFC][17];
    float a_[120], dvec[120];
    float Avec[16], Bvec[16];
    float Gc[COUT][KS], cb2[COUT];
    float y[COUT][22];
};

union alignas(16) Sm { MnSm m; BrSm b; };

__device__ inline float wred(float v) {
    #pragma unroll
    for (int off = 32; off; off >>= 1) v += __shfl_xor(v, off);
    return v;
}

__device__ inline void postM(int* f, int tid) {
    __syncthreads();
    if (tid == 0)
        __hip_atomic_store(f, MAGIC, __ATOMIC_RELEASE, __HIP_MEMORY_SCOPE_AGENT);
}

__device__ inline void waitM(int* base, int first, int n, int tid) {
    if (tid == 0) {
        for (int i = 0; i < n; ++i) {
            int* f = base + (first + i) * 16;
            while (__hip_atomic_load(f, __ATOMIC_RELAXED, __HIP_MEMORY_SCOPE_AGENT) != MAGIC)
                __builtin_amdgcn_s_sleep(1);
        }
        __builtin_amdgcn_fence(__ATOMIC_ACQUIRE, "agent");
    }
    __syncthreads();
}

// ---------------------------------------------------------------------------
// q/k projection task (blocks 2..19), R9 direct-global pattern, tasks 0..69:
//  task<30: q (4 o-cols x 16 r); else k (3 o-cols x 21 r).
// ---------------------------------------------------------------------------
__device__ void qk_task(int side, int lw, int lane, const Params& p)
{
    int sec, o, r, R;
    if (lw < 30) { sec = 0; o = lw * 4 + (lane & 3); r = lane >> 2; R = 16; }
    else         { sec = 1; o = (lw - 30) * 3 + lane % 3; r = lane / 3; R = TDN; }
    if (o >= OFC || r >= R) return;

    const float* in_w = (side ? p.tdB_in_w : p.tdA_in_w) + sec * IW_SZ + o * OFC;
    const float  bias = (side ? p.tdB_in_b : p.tdA_in_b)[sec * OFC + o];
    const float2* w2  = (const float2*)in_w;
    float s0 = 0.f;

    if (sec == 0) {
        const float2* a = (const float2*)(p.x + (1 + r) * WL + (WL - OFC));
        #pragma unroll 4
        for (int j = 0; j < 59; ++j) {
            float2 u = a[j], w = w2[j];
            s0 += u.x * w.x + u.y * w.y;
        }
        s0 = (s0 + bias) * (1.0f / sqrtf(118.0f));
    } else {
        const float* wr = p.x + (side ? 17 * WL : 0) + r;
        #pragma unroll 4
        for (int j = 0; j < 59; ++j) {
            float2 w = w2[j];
            s0 += wr[2 * j] * w.x + wr[2 * j + 1] * w.y;
        }
        s0 += bias;
    }
    p.ws[side * PROJ_STRIDE + (sec == 0 ? 0 : KP_OFF) + r * OFC + o] = s0;
}

// ---------------------------------------------------------------------------
// main block (0,1): pre-wait {stage wout/eeg/bout/fc, vp direct-global, vpw},
// then wait qk -> scores -> wave-softmax -> acs -> colsum -> select -> att.
// ---------------------------------------------------------------------------
__device__ void main_block(int b, int tid, const Params& p, MnSm& s)
{
    const int wid = tid >> 6, lane = tid & 63;
    int* flags = (int*)(p.ws + WS_FLAGS);

    // ---- pre-wait staging (L2 warm, pre-invalidate) ----
    const float* ow = b ? p.tdB_out_w : p.tdA_out_w;
    for (int e = tid; e < OFC * 59; e += 512) {
        int o = e / 59, j = e - o * 59;
        ((float2*)&s.wout[o][0])[j] = ((const float2*)(ow + o * OFC))[j];
    }
    for (int e = tid; e < 16 * OFC; e += 512) {
        int r = e / OFC, c = e - (e / OFC) * OFC;
        s.eeg[r][c] = p.x[(1 + r) * WL + (WL - OFC) + c];
    }
    if (tid < OFC) s.bout[tid] = (b ? p.tdB_out_b : p.tdA_out_b)[tid];
    if (b == 0) {
        for (int e = tid; e < 1600; e += 512) s.fc1w[e] = p.fc1_w[e];
        if (tid < 40) s.fc1b[tid] = p.fc1_b[tid];
        if (tid >= 64 && tid < 144) s.fc2w[tid - 64] = p.fc2_w[tid - 64];
        if (tid >= 160 && tid < 162) s.fc2b[tid - 160] = p.fc2_b[tid - 160];
    }

    // ---- vp: direct-global wave tasks (40 tasks over 8 waves, 5 rounds) ----
    {
        const float* in_w = (b ? p.tdB_in_w : p.tdA_in_w) + 2 * IW_SZ;
        const float* in_b = (b ? p.tdB_in_b : p.tdA_in_b) + 2 * OFC;
        const float* wav  = p.x + (b ? 17 * WL : 0);
        for (int rd = 0; rd < 5; ++rd) {
            int task = rd * 8 + wid;
            if (task < 40) {
                int o = task * 3 + lane % 3, r = lane / 3;
                if (o < OFC && r < TDN) {
                    const float2* w2 = (const float2*)(in_w + o * OFC);
                    const float* wr = wav + r;
                    float s0 = 0.f;
                    #pragma unroll 4
                    for (int j = 0; j < 59; ++j) {
                        float2 w = w2[j];
                        s0 += wr[2 * j] * w.x + wr[2 * j + 1] * w.y;
                    }
                    s.vp[r][o] = s0 + in_b[o];
                }
            }
        }
    }
    __syncthreads();

    // ---- vpw[t][j] = vp[t] . wout[j] ----
    for (int e = tid; e < TDN * OFC; e += 512) {
        int t = e / OFC, j = e - t * OFC;
        const float2* a  = (const float2*)&s.vp[t][0];
        const float2* w2 = (const float2*)&s.wout[j][0];
        float acc = 0.f;
        #pragma unroll 4
        for (int oo = 0; oo < 59; ++oo) {
            float2 u = a[oo], w = w2[oo];
            acc += u.x * w.x + u.y * w.y;
        }
        s.vpw[t][j] = acc;
    }

    // ---- wait for q/k, stage them ----
    waitM(flags, b * 9, 9, tid);
    const float* base = p.ws + b * PROJ_STRIDE;
    for (int e = tid; e < 16 * 59; e += 512) {
        int r = e / 59, j = e - r * 59;
        ((float2*)&s.qpp[r][0])[j] = ((const float2*)(base + r * OFC))[j];
    }
    for (int e = tid; e < TDN * 59; e += 512) {
        int t = e / 59, j = e - t * 59;
        ((float2*)&s.kpp[t][0])[j] = ((const float2*)(base + KP_OFF + t * OFC))[j];
    }
    __syncthreads();

    // ---- scores 16x21 ----
    if (tid < 16 * TDN) {
        int i = tid / TDN, t = tid - (tid / TDN) * TDN;
        const float2* q = (const float2*)&s.qpp[i][0];
        const float2* k = (const float2*)&s.kpp[t][0];
        float sc = 0.f;
        #pragma unroll 4
        for (int j = 0; j < 59; ++j) {
            float2 u = q[j], v = k[j];
            sc += u.x * v.x + u.y * v.y;
        }
        s.attn[i][t] = sc;
    }
    __syncthreads();

    // ---- wave-parallel softmax: wave w rows {2w, 2w+1}, 32-lane groups ----
    {
        int row = wid * 2 + (lane >= 32 ? 1 : 0);
        int t   = lane & 31;
        float v = (t < TDN) ? s.attn[row][t] : -INFINITY;
        float m = v;
        #pragma unroll
        for (int off = 16; off; off >>= 1) m = fmaxf(m, __shfl_xor(m, off, 32));
        float pp = (t < TDN) ? __expf(v - m) : 0.f;
        float l = pp;
        #pragma unroll
        for (int off = 16; off; off >>= 1) l += __shfl_xor(l, off, 32);
        if (t < TDN) s.attn[row][t] = pp / l;
    }
    __syncthreads();

    if (tid < TDN) {
        float a = 0.f;
        for (int i = 0; i < 16; ++i) a += s.attn[i][tid];
        s.acs[tid] = a;
    }
    __syncthreads();

    // ---- colsum[j] = sum_t acs[t]*vpw[t][j] + 16*b_out[j] ----
    if (tid < OFC) {
        float a = 0.f;
        #pragma unroll 3
        for (int t = 0; t < TDN; ++t) a += s.acs[t] * s.vpw[t][tid];
        s.colsum[tid] = a + 16.f * s.bout[tid];
    }
    __syncthreads();

    // ---- Ssum[i] = eeg[i] . colsum ----
    for (int d = wid; d < 16; d += 8) {
        int j0 = lane * 2;
        float sc = 0.f;
        if (j0 < OFC) {
            float2 ev = *(const float2*)(&s.eeg[d][j0]);
            float2 cv = *(const float2*)(&s.colsum[j0]);
            sc = ev.x * cv.x + ev.y * cv.y;
        }
        sc = wred(sc);
        if (lane == 0) s.Ssum[d] = sc;
    }
    __syncthreads();

    if (tid == 0) {
        int best = 0; float bv = s.Ssum[0];
        for (int i = 1; i < 16; ++i)
            if (s.Ssum[i] > bv) { bv = s.Ssum[i]; best = i; }   // first-max
        s.sel = best;
    }
    __syncthreads();

    // ---- att_sel[j] = sum_t attn[sel][t]*vpw[t][j] + b_out[j] ----
    if (tid < OFC) {
        float a = 0.f;
        #pragma unroll 3
        for (int t = 0; t < TDN; ++t) a += s.attn[s.sel][t] * s.vpw[t][tid];
        p.ws[(b ? WS_ATT_B : WS_ATT_A) + tid] = a + s.bout[tid];
    }
    postM(&flags[(18 + b) * 16], tid);

    // ---- head (block 0) ----
    if (b == 0) {
        waitM(flags, 20, 4, tid);
        if (tid < NSLOTS)
            __hip_atomic_store(&flags[tid * 16], 0,
                               __ATOMIC_RELAXED, __HIP_MEMORY_SCOPE_AGENT);
        if (tid < 40) s.hf[tid] = p.ws[WS_FEATS + tid];
        __syncthreads();
        if (tid < 40) {
            float a = s.fc1b[tid];
            for (int k = 0; k < 40; ++k) a += s.hf[k] * s.fc1w[tid * 40 + k];
            s.hh[tid] = 1.f / (1.f + __expf(-a));
        }
        __syncthreads();
        if (tid < 2) {
            float a = s.fc2b[tid];
            for (int k = 0; k < 40; ++k) a += s.hh[k] * s.fc2w[tid * 40 + k];
            p.out[tid] = 1.f / (1.f + __expf(-a));
        }
    }
}

// ---------------------------------------------------------------------------
// branch prestage (blocks 20..23)
// ---------------------------------------------------------------------------
__device__ void br_pre(int br, int tid, const Params& p, BrSm& s)
{
    const bool d_r1 = (br == 0 || br == 3);

    for (int e = tid; e < 16 * OFC; e += 512) {
        int r = e / OFC, c = e - (e / OFC) * OFC;
        s.eeg_s[r][c] = p.x[(1 + r) * WL + (WL - OFC) + c];
    }
    for (int e = tid; e < 768; e += 512) {
        int q = e / 16, r = e % 16;
        s.w_inT[r][q] = p.cm_in_w[br * 768 + e];
    }
    if (tid < 48) s.b_in[tid] = p.cm_in_b[br * 48 + tid];
    if (tid >= 64 && tid < 320) {
        int e = tid - 64;
        s.w_out[e >> 4][e & 15] = p.cm_out_w[br * 256 + e];
    }
    if (tid >= 384 && tid < 400) s.b_out[tid - 384] = p.cm_out_b[br * 16 + (tid - 384)];
    for (int e = tid; e < COUT * 16 * KS; e += 512) s.cw[e] = p.conv_w[br * 1440 + e];
    if (tid >= 400 && tid < 410) s.cb[tid - 400] = p.conv_b[br * COUT + (tid - 400)];
    {
        const float* pvg = (br < 2) ? p.projA_w : p.projB_w;
        if (tid >= 416 && tid < 432) s.pv[tid - 416] = pvg[tid - 416];
    }
    __syncthreads();

    if (tid < 48) {
        float a = 0.f;
        #pragma unroll
        for (int r = 0; r < 16; ++r) a += s.pv[r] * s.w_inT[r][tid];
        s.tv[tid / 16][tid % 16] = a;
    }
    __syncthreads();

    if (d_r1) {
        for (int e = tid; e < 2 * OFC * 16; e += 512) {
            int sec01 = e / (OFC * 16);
            int rem = e - sec01 * OFC * 16;
            int j = rem >> 4, o = rem & 15;
            float a = 0.f;
            #pragma unroll
            for (int r = 0; r < 16; ++r) a += s.eeg_s[r][j] * s.w_inT[r][(1 + sec01) * 16 + o];
            a += s.b_in[(1 + sec01) * 16 + o];
            (sec01 ? &s.vpS[0][0] : &s.kpS[0][0])[j * 17 + o] = a;
        }
        __syncthreads();
        if (tid < OFC) {
            float uu = 0.f, vv = 0.f;
            #pragma unroll
            for (int o = 0; o < 16; ++o) {
                float kv = s.kpS[tid][o];
                uu += s.tv[0][o] * kv;
                vv += s.b_in[o] * kv;
            }
            s.u[tid] = uu; s.v2[tid] = vv;
        }
    } else {
        for (int e = tid; e < OFC * 16; e += 512) {
            int j = e >> 4, o = e & 15;
            float a = 0.f;
            #pragma unroll
            for (int r = 0; r < 16; ++r) a += s.eeg_s[r][j] * s.w_inT[r][o];
            s.qpS[j][o] = (a + s.b_in[o]) * 0.25f;
        }
        __syncthreads();
        if (tid < OFC) {
            float a = 0.f;
            #pragma unroll
            for (int o = 0; o < 16; ++o) a += s.qpS[tid][o] * s.tv[1][o];
            s.a_[tid] = a;
        }
        if (tid >= 128 && tid < 144) {
            int c = tid - 128;
            float A = 0.f, B = 0.f;
            #pragma unroll
            for (int o = 0; o < 16; ++o) {
                A += s.tv[2][o] * s.w_out[c][o];
                B += s.b_in[32 + o] * s.w_out[c][o];
            }
            s.Avec[c] = A;
            s.Bvec[c] = B + s.b_out[c];
        }
        __syncthreads();
        if (tid < COUT * KS) {
            int c = tid / KS, k = tid - (tid / KS) * KS;
            float g = 0.f;
            #pragma unroll
            for (int m = 0; m < 16; ++m) g += s.Avec[m] * s.cw[(c * 16 + m) * KS + k];
            s.Gc[c][k] = g;
        }
        if (tid >= 128 && tid < 128 + COUT) {
            int c = tid - 128;
            float cc = s.cb[c];
            #pragma unroll
            for (int m = 0; m < 16; ++m) {
                float bsum = 0.f;
                #pragma unroll
                for (int k = 0; k < KS; ++k) bsum += s.cw[(c * 16 + m) * KS + k];
                cc += s.Bvec[m] * bsum;
            }
            s.cb2[c] = cc;
        }
    }
}

// ---------------------------------------------------------------------------
// branch main (blocks 20..23)
// ---------------------------------------------------------------------------
__device__ void br_main(int br, int tid, const Params& p, BrSm& s)
{
    const bool d_r1 = (br == 0 || br == 3);
    const float* ar = p.ws + ((br < 2) ? WS_ATT_A : WS_ATT_B);
    if (tid < OFC) s.arow[tid] = ar[tid];
    __syncthreads();

    if (d_r1) {
        const int g = tid >> 7, j = tid & 127;
        float acc[16];
        float m = -INFINITY, l = 0.f;
        #pragma unroll
        for (int r = 0; r < 16; ++r) acc[r] = 0.f;

        if (j < OFC) {
            const float aj = s.arow[j];
            const int t0 = (g * OFC) >> 2, t1 = ((g + 1) * OFC) >> 2;
            for (int t = t0; t < t1; ++t) {
                float sc = 0.25f * fmaf(aj, s.u[t], s.v2[t]);
                float mn = fmaxf(m, sc);
                float c  = __expf(m - mn);
                float pp = __expf(sc - mn);
                l = l * c + pp;
                const float* vr = &s.vpS[t][0];
                #pragma unroll
                for (int r = 0; r < 16; ++r) acc[r] = acc[r] * c + pp * vr[r];
                m = mn;
            }
            s.part_m[g][j] = m;
            s.part_l[g][j] = l;
            #pragma unroll
            for (int r = 0; r < 16; ++r) s.part_acc[g][j][r] = acc[r];
        }
        __syncthreads();

        if (tid < OFC) {
            float m0 = s.part_m[0][tid], m1 = s.part_m[1][tid];
            float m2 = s.part_m[2][tid], m3 = s.part_m[3][tid];
            float mm = fmaxf(fmaxf(m0, m1), fmaxf(m2, m3));
            float c0 = __expf(m0 - mm), c1 = __expf(m1 - mm);
            float c2 = __expf(m2 - mm), c3 = __expf(m3 - mm);
            float ll = c0 * s.part_l[0][tid] + c1 * s.part_l[1][tid]
                     + c2 * s.part_l[2][tid] + c3 * s.part_l[3][tid];
            float inv = 1.f / ll;
            float orow[16];
            #pragma unroll
            for (int r = 0; r < 16; ++r)
                orow[r] = (c0 * s.part_acc[0][tid][r] + c1 * s.part_acc[1][tid][r]
                         + c2 * s.part_acc[2][tid][r] + c3 * s.part_acc[3][tid][r]) * inv;
            for (int c = 0; c < 16; ++c) {
                float a = s.b_out[c];
                #pragma unroll
                for (int d = 0; d < 16; ++d) a += orow[d] * s.w_out[c][d];
                s.o2[tid][c] = a;
            }
        }
        __syncthreads();

        if (tid < COUT * 22) {
            int c = tid / 22, grp = tid - (tid / 22) * 22;
            int pbase = grp * 5;
            float acc5[5];
            #pragma unroll
            for (int i = 0; i < 5; ++i) acc5[i] = s.cb[c];
            for (int mI = 0; mI < 16; ++mI) {
                float win[13];
                #pragma unroll
                for (int t = 0; t < 13; ++t) win[t] = s.o2[pbase + t][mI];
                #pragma unroll
                for (int k = 0; k < KS; ++k) {
                    float wv = s.cw[(c * 16 + mI) * KS + k];
                    #pragma unroll
                    for (int i = 0; i < 5; ++i) acc5[i] += win[i + k] * wv;
                }
            }
            float mx = fmaxf(fmaxf(fmaxf(acc5[0], acc5[1]), fmaxf(acc5[2], acc5[3])), acc5[4]);
            s.y[c][grp] = fmaxf(mx, 0.f);
        }
        __syncthreads();
    } else {
        if (tid < OFC) {
            const float aj = s.a_[tid];
            float m = -INFINITY;
            for (int t = 0; t < OFC; ++t) m = fmaxf(m, aj * s.arow[t]);
            float l = 0.f, d = 0.f;
            for (int t = 0; t < OFC; ++t) {
                float e = __expf(aj * s.arow[t] - m);
                l += e;
                d += e * s.arow[t];
            }
            s.dvec[tid] = d / l;
        }
        __syncthreads();

        if (tid < COUT * 22) {
            int c = tid / 22, grp = tid - (tid / 22) * 22;
            int pbase = grp * 5;
            float win[13];
            #pragma unroll
            for (int t = 0; t < 13; ++t) win[t] = s.dvec[pbase + t];
            float acc5[5];
            #pragma unroll
            for (int i = 0; i < 5; ++i) acc5[i] = s.cb2[c];
            #pragma unroll
            for (int k = 0; k < KS; ++k) {
                float wv = s.Gc[c][k];
                #pragma unroll
                for (int i = 0; i < 5; ++i) acc5[i] += win[i + k] * wv;
            }
            float mx = fmaxf(fmaxf(fmaxf(acc5[0], acc5[1]), fmaxf(acc5[2], acc5[3])), acc5[4]);
            s.y[c][grp] = fmaxf(mx, 0.f);
        }
        __syncthreads();
    }

    if (tid < COUT) {
        float mx = s.y[tid][0];
        for (int g2 = 1; g2 < 22; ++g2) mx = fmaxf(mx, s.y[tid][g2]);
        p.ws[WS_FEATS + br * COUT + tid] = mx;
    }
}

// ---------------------------------------------------------------------------
__global__ __launch_bounds__(512) void fused_net(Params p)
{
    __shared__ Sm sm;
    const int blk = blockIdx.x;
    const int tid = threadIdx.x;
    int* flags = (int*)(p.ws + WS_FLAGS);

    if (blk >= 2 && blk < 20) {
        // q/k projections: blocks 2..10 side A, 11..19 side B (9 each)
        const int side = (blk < 11) ? 0 : 1;
        const int gw   = (blk - (side ? 11 : 2)) * 8 + (tid >> 6);
        if (gw < 70) qk_task(side, gw, tid & 63, p);
        postM(&flags[(blk - 2) * 16], tid);
        return;
    }

    if (blk < 2) {
        main_block(blk, tid, p, sm.m);
        return;
    }

    const int br = blk - 20;
    br_pre(br, tid, p, sm.b);
    waitM(flags, (br < 2) ? 18 : 19, 1, tid);
    br_main(br, tid, p, sm.b);
    postM(&flags[(20 + br) * 16], tid);
}

// ---------------------------------------------------------------------------
extern "C" void kernel_launch(void* const* d_in, const int* in_sizes, int n_in,
                              void* d_out, int out_size, void* d_ws, size_t ws_size,
                              hipStream_t stream) {
    Params prm;
    prm.x         = (const float*)d_in[0];
    prm.tdA_in_w  = (const float*)d_in[1];
    prm.tdA_in_b  = (const float*)d_in[2];
    prm.tdA_out_w = (const float*)d_in[3];
    prm.tdA_out_b = (const float*)d_in[4];
    prm.tdB_in_w  = (const float*)d_in[5];
    prm.tdB_in_b  = (const float*)d_in[6];
    prm.tdB_out_w = (const float*)d_in[7];
    prm.tdB_out_b = (const float*)d_in[8];
    prm.cm_in_w   = (const float*)d_in[9];
    prm.cm_in_b   = (const float*)d_in[10];
    prm.cm_out_w  = (const float*)d_in[11];
    prm.cm_out_b  = (const float*)d_in[12];
    prm.projA_w   = (const float*)d_in[13];
    prm.projB_w   = (const float*)d_in[14];
    prm.conv_w    = (const float*)d_in[15];
    prm.conv_b    = (const float*)d_in[16];
    prm.fc1_w     = (const float*)d_in[17];
    prm.fc1_b     = (const float*)d_in[18];
    prm.fc2_w     = (const float*)d_in[19];
    prm.fc2_b     = (const float*)d_in[20];
    prm.ws        = (float*)d_ws;
    prm.out       = (float*)d_out;

    fused_net<<<dim3(24), dim3(512), 0, stream>>>(prm);
}

// Round 11
// 46.259 us; speedup vs baseline: 1.5454x; 1.5454x over previous
//
#include <hip/hip_runtime.h>
#include <math.h>

#define WL   140
#define OFC  118
#define TDN  21
#define COUT 10
#define KS   9
#define IW_SZ (OFC * OFC)       // 13924

// ws layout (floats)
#define PROJ_STRIDE 6848
#define KP_OFF      1888
#define VP_OFF      4368
#define WS_FEATS    13952
#define WS_FLAGS    14080

// flag slots (stride 16 ints): proj blocks 2..29 -> slot blk-2 (0..27);
// featsB = 28. 29 slots, self-resetting via MAGIC protocol.
#define MAGIC  0x1F2E3D4C
#define NSLOTS 29

struct Params {
    const float *x;
    const float *tdA_in_w, *tdA_in_b, *tdA_out_w, *tdA_out_b;
    const float *tdB_in_w, *tdB_in_b, *tdB_out_w, *tdB_out_b;
    const float *cm_in_w, *cm_in_b, *cm_out_w, *cm_out_b;
    const float *projA_w, *projB_w, *conv_w, *conv_b;
    const float *fc1_w, *fc1_b, *fc2_w, *fc2_b;
    float *ws, *out;
};

// ---- LDS plan -------------------------------------------------------------
struct PreScratch {               // branch prestage scratch (pre-wait only)
    float w_inT[16][48];
    float b_in[48];
    float pv[16];
    float kpS[OFC][17];
    float qpS[OFC][17];
    float tv[3][16];
    float w_out_kr[16][16];
    float b_out_kr[16];
    float cw_kr[COUT * 16 * KS];
    float cb_kr[16];
    float Avec[16], Bvec[16];
};                                 // ~26.7 KB  (must fit QkvStage: 28.3 KB)

struct QkvStage {                  // staged q/k/v (post-wait)
    float qpp[16][122];
    float kpp[TDN][122];
    float vpp[TDN][122];
};

struct Ph {                        // phase-2 state
    float owpad[OFC][122];         // 57.6 KB
    union { QkvStage qkv; PreScratch pre; } u2;
};

struct BrScratch {                 // branch-phase scratch (aliases dead owpad)
    float part_m[4][128];
    float part_l[4][128];
    float part_acc[4][OFC][17];
    float o2[OFC][17];
    float dvec[120];
    float y[COUT][22];
};                                 // ~45.6 KB < 57.6 KB

struct MnSm {
    union { Ph ph; BrScratch br; } u1;
    float attn[16][22];
    float acs[24];
    float avcs[120];
    float colsum[120];
    float Ssum[16];
    float avsel[120];
    int   sel;
};

struct Pers {                      // persistent across the whole block
    float arow[120];
    float eeg[16][120];
    float bout[120];
    float u[120], v2[120];         // d_r1 branch
    float vpS[OFC][17];            // d_r1 V (eeg-projected)
    float w_out_dr[16][16];
    float b_out_dr[16];
    float cw_dr[COUT * 16 * KS];
    float cb_dr[16];
    float a_[120];                 // kv-r1 branch
    float Gc[COUT][KS];
    float cb2[16];
    float feats[40];
    float fc1w[1600], fc1b[40], fc2w[80], fc2b[2];
    float hh[40];
};

struct Sm { MnSm m; Pers p; };     // ~122 KB

__device__ inline float wred(float v) {
    #pragma unroll
    for (int off = 32; off; off >>= 1) v += __shfl_xor(v, off);
    return v;
}

__device__ inline void postM(int* f, int tid) {
    __syncthreads();
    if (tid == 0)
        __hip_atomic_store(f, MAGIC, __ATOMIC_RELEASE, __HIP_MEMORY_SCOPE_AGENT);
}

__device__ inline void waitM(int* base, int first, int n, int tid) {
    if (tid == 0) {
        for (int i = 0; i < n; ++i) {
            int* f = base + (first + i) * 16;
            while (__hip_atomic_load(f, __ATOMIC_RELAXED, __HIP_MEMORY_SCOPE_AGENT) != MAGIC)
                __builtin_amdgcn_s_sleep(1);
        }
        __builtin_amdgcn_fence(__ATOMIC_ACQUIRE, "agent");
    }
    __syncthreads();
}

// ---------------------------------------------------------------------------
// q/k/v projection task (blocks 2..29), direct-global, 110 tasks per side:
//  task<30: q (4 o x 16 r); <70: k (3 o x 21 r); <110: v (3 o x 21 r).
// ---------------------------------------------------------------------------
__device__ void proj_task(int side, int lw, int lane, const Params& p)
{
    int sec, o, r, R;
    if (lw < 30) { sec = 0; o = lw * 4 + (lane & 3); r = lane >> 2; R = 16; }
    else if (lw < 70) { sec = 1; o = (lw - 30) * 3 + lane % 3; r = lane / 3; R = TDN; }
    else { sec = 2; o = (lw - 70) * 3 + lane % 3; r = lane / 3; R = TDN; }
    if (o >= OFC || r >= R) return;

    const float* in_w = (side ? p.tdB_in_w : p.tdA_in_w) + sec * IW_SZ + o * OFC;
    const float  bias = (side ? p.tdB_in_b : p.tdA_in_b)[sec * OFC + o];
    const float2* w2  = (const float2*)in_w;
    float s0 = 0.f;

    if (sec == 0) {
        const float2* a = (const float2*)(p.x + (1 + r) * WL + (WL - OFC));
        #pragma unroll 4
        for (int j = 0; j < 59; ++j) {
            float2 u = a[j], w = w2[j];
            s0 += u.x * w.x + u.y * w.y;
        }
        s0 = (s0 + bias) * (1.0f / sqrtf(118.0f));
    } else {
        const float* wr = p.x + (side ? 17 * WL : 0) + r;
        #pragma unroll 4
        for (int j = 0; j < 59; ++j) {
            float2 w = w2[j];
            s0 += wr[2 * j] * w.x + wr[2 * j + 1] * w.y;
        }
        s0 += bias;
    }
    p.ws[side * PROJ_STRIDE
         + (sec == 0 ? 0 : (sec == 1 ? KP_OFF : VP_OFF))
         + r * OFC + o] = s0;
}

// ---------------------------------------------------------------------------
// main block b in {0,1}: prestage + branch-precompute (overlaps proj), wait,
// phase2 (attn row-select), inline branches, feats exchange, head (b==0).
// ---------------------------------------------------------------------------
__device__ void main_block(int b, int tid, const Params& p, Sm& S)
{
    const int wid = tid >> 6, lane = tid & 63;
    int* flags = (int*)(p.ws + WS_FLAGS);
    MnSm& m = S.m;
    Pers& P = S.p;
    const int dr = b ? 3 : 0;          // data-rank1 branch (flash over eeg kv)
    const int kr = b ? 2 : 1;          // kv-rank1 branch (collapsed)
    const float* pvg = b ? p.projB_w : p.projA_w;
    PreScratch& pr = m.u1.ph.u2.pre;

    // ================= pre-wait: staging =================
    const float* ow = b ? p.tdB_out_w : p.tdA_out_w;
    for (int e = tid; e < OFC * 59; e += 512) {
        int o = e / 59, j = e - o * 59;
        ((float2*)&m.u1.ph.owpad[o][0])[j] = ((const float2*)(ow + o * OFC))[j];
    }
    for (int e = tid; e < 16 * OFC; e += 512) {
        int r = e / OFC, c = e - (e / OFC) * OFC;
        P.eeg[r][c] = p.x[(1 + r) * WL + (WL - OFC) + c];
    }
    if (tid < OFC) P.bout[tid] = (b ? p.tdB_out_b : p.tdA_out_b)[tid];
    for (int e = tid; e < 1440; e += 512) P.cw_dr[e] = p.conv_w[dr * 1440 + e];
    if (tid < 256) P.w_out_dr[tid >> 4][tid & 15] = p.cm_out_w[dr * 256 + tid];
    if (tid >= 256 && tid < 272) P.b_out_dr[tid - 256] = p.cm_out_b[dr * 16 + (tid - 256)];
    if (tid >= 288 && tid < 288 + COUT) P.cb_dr[tid - 288] = p.conv_b[dr * COUT + (tid - 288)];
    if (b == 0) {
        for (int e = tid; e < 1600; e += 512) P.fc1w[e] = p.fc1_w[e];
        if (tid < 40) P.fc1b[tid] = p.fc1_b[tid];
        if (tid >= 320 && tid < 400) P.fc2w[tid - 320] = p.fc2_w[tid - 320];
        if (tid >= 400 && tid < 402) P.fc2b[tid - 400] = p.fc2_b[tid - 400];
    }
    for (int e = tid; e < 768; e += 512) {
        int q = e / 16, r = e % 16;
        pr.w_inT[r][q] = p.cm_in_w[dr * 768 + e];
    }
    if (tid < 48) pr.b_in[tid] = p.cm_in_b[dr * 48 + tid];
    if (tid >= 448 && tid < 464) pr.pv[tid - 448] = pvg[tid - 448];
    __syncthreads();

    // ======= pre-wait: d_r1 branch precompute (no arow needed) =======
    if (tid < 16) {
        float a = 0.f;
        #pragma unroll
        for (int r = 0; r < 16; ++r) a += pr.pv[r] * pr.w_inT[r][tid];
        pr.tv[0][tid] = a;
    }
    __syncthreads();
    for (int e = tid; e < 2 * OFC * 16; e += 512) {    // eeg k/v projections
        int sec01 = e / (OFC * 16);
        int rem = e - sec01 * OFC * 16;
        int j = rem >> 4, o = rem & 15;
        float a = 0.f;
        #pragma unroll
        for (int r = 0; r < 16; ++r) a += P.eeg[r][j] * pr.w_inT[r][(1 + sec01) * 16 + o];
        a += pr.b_in[(1 + sec01) * 16 + o];
        if (sec01) P.vpS[j][o] = a; else pr.kpS[j][o] = a;
    }
    __syncthreads();
    if (tid < OFC) {
        float uu = 0.f, vv = 0.f;
        #pragma unroll
        for (int o = 0; o < 16; ++o) {
            float kv = pr.kpS[tid][o];
            uu += pr.tv[0][o] * kv;
            vv += pr.b_in[o] * kv;
        }
        P.u[tid] = uu; P.v2[tid] = vv;
    }
    __syncthreads();

    // ======= pre-wait: kv-r1 branch precompute =======
    for (int e = tid; e < 768; e += 512) {
        int q = e / 16, r = e % 16;
        pr.w_inT[r][q] = p.cm_in_w[kr * 768 + e];
    }
    if (tid < 48) pr.b_in[tid] = p.cm_in_b[kr * 48 + tid];
    if (tid >= 64 && tid < 320) {
        int e = tid - 64;
        pr.w_out_kr[e >> 4][e & 15] = p.cm_out_w[kr * 256 + e];
    }
    if (tid >= 320 && tid < 336) pr.b_out_kr[tid - 320] = p.cm_out_b[kr * 16 + (tid - 320)];
    for (int e = tid; e < 1440; e += 512) pr.cw_kr[e] = p.conv_w[kr * 1440 + e];
    if (tid >= 336 && tid < 336 + COUT) pr.cb_kr[tid - 336] = p.conv_b[kr * COUT + (tid - 336)];
    __syncthreads();
    if (tid < 48) {
        float a = 0.f;
        #pragma unroll
        for (int r = 0; r < 16; ++r) a += pr.pv[r] * pr.w_inT[r][tid];
        pr.tv[tid / 16][tid % 16] = a;
    }
    __syncthreads();
    for (int e = tid; e < OFC * 16; e += 512) {        // eeg q projection
        int j = e >> 4, o = e & 15;
        float a = 0.f;
        #pragma unroll
        for (int r = 0; r < 16; ++r) a += P.eeg[r][j] * pr.w_inT[r][o];
        pr.qpS[j][o] = (a + pr.b_in[o]) * 0.25f;
    }
    __syncthreads();
    if (tid < OFC) {
        float a = 0.f;
        #pragma unroll
        for (int o = 0; o < 16; ++o) a += pr.qpS[tid][o] * pr.tv[1][o];
        P.a_[tid] = a;
    }
    if (tid >= 128 && tid < 144) {
        int c = tid - 128;
        float A = 0.f, B = 0.f;
        #pragma unroll
        for (int o = 0; o < 16; ++o) {
            A += pr.tv[2][o] * pr.w_out_kr[c][o];
            B += pr.b_in[32 + o] * pr.w_out_kr[c][o];
        }
        pr.Avec[c] = A;
        pr.Bvec[c] = B + pr.b_out_kr[c];
    }
    __syncthreads();
    if (tid < COUT * KS) {
        int c = tid / KS, k = tid - (tid / KS) * KS;
        float g = 0.f;
        #pragma unroll
        for (int mm = 0; mm < 16; ++mm) g += pr.Avec[mm] * pr.cw_kr[(c * 16 + mm) * KS + k];
        P.Gc[c][k] = g;
    }
    if (tid >= 128 && tid < 128 + COUT) {
        int c = tid - 128;
        float cc = pr.cb_kr[c];
        #pragma unroll
        for (int mm = 0; mm < 16; ++mm) {
            float bs = 0.f;
            #pragma unroll
            for (int k = 0; k < KS; ++k) bs += pr.cw_kr[(c * 16 + mm) * KS + k];
            cc += pr.Bvec[mm] * bs;
        }
        P.cb2[c] = cc;
    }

    // ================= wait for q/k/v, stage =================
    waitM(flags, b * 14, 14, tid);                     // barrier inside
    const float* base = p.ws + b * PROJ_STRIDE;
    QkvStage& st = m.u1.ph.u2.qkv;                     // aliases pr (now dead)
    for (int e = tid; e < 16 * 59; e += 512) {
        int r = e / 59, j = e - r * 59;
        ((float2*)&st.qpp[r][0])[j] = ((const float2*)(base + r * OFC))[j];
    }
    for (int e = tid; e < TDN * 59; e += 512) {
        int t = e / 59, j = e - t * 59;
        ((float2*)&st.kpp[t][0])[j] = ((const float2*)(base + KP_OFF + t * OFC))[j];
        ((float2*)&st.vpp[t][0])[j] = ((const float2*)(base + VP_OFF + t * OFC))[j];
    }
    __syncthreads();

    // ================= phase 2 =================
    if (tid < 16 * TDN) {
        int i = tid / TDN, t = tid - (tid / TDN) * TDN;
        const float2* q = (const float2*)&st.qpp[i][0];
        const float2* k = (const float2*)&st.kpp[t][0];
        float sc = 0.f;
        #pragma unroll 4
        for (int j = 0; j < 59; ++j) {
            float2 u = q[j], v = k[j];
            sc += u.x * v.x + u.y * v.y;
        }
        m.attn[i][t] = sc;
    }
    __syncthreads();

    {   // wave-parallel softmax: wave w rows {2w,2w+1}, 32-lane groups
        int row = wid * 2 + (lane >= 32 ? 1 : 0);
        int t   = lane & 31;
        float v = (t < TDN) ? m.attn[row][t] : -INFINITY;
        float mx = v;
        #pragma unroll
        for (int off = 16; off; off >>= 1) mx = fmaxf(mx, __shfl_xor(mx, off, 32));
        float pp = (t < TDN) ? __expf(v - mx) : 0.f;
        float l = pp;
        #pragma unroll
        for (int off = 16; off; off >>= 1) l += __shfl_xor(l, off, 32);
        if (t < TDN) m.attn[row][t] = pp / l;
    }
    __syncthreads();

    if (tid < TDN) {
        float a = 0.f;
        for (int i = 0; i < 16; ++i) a += m.attn[i][tid];
        m.acs[tid] = a;
    }
    __syncthreads();

    if (tid < OFC) {
        float a = 0.f;
        #pragma unroll 3
        for (int t = 0; t < TDN; ++t) a += m.acs[t] * st.vpp[t][tid];
        m.avcs[tid] = a;
    }
    __syncthreads();

    if (tid < OFC) {
        const float2* a  = (const float2*)&m.avcs[0];
        const float2* w2 = (const float2*)&m.u1.ph.owpad[tid][0];
        float a0 = 0.f;
        #pragma unroll 4
        for (int j = 0; j < 59; ++j) {
            float2 u = a[j], v = w2[j];
            a0 += u.x * v.x + u.y * v.y;
        }
        m.colsum[tid] = a0 + 16.f * P.bout[tid];
    }
    __syncthreads();

    for (int d = wid; d < 16; d += 8) {
        int j0 = lane * 2;
        float sc = 0.f;
        if (j0 < OFC) {
            float2 ev = *(const float2*)(&P.eeg[d][j0]);
            float2 cv = *(const float2*)(&m.colsum[j0]);
            sc = ev.x * cv.x + ev.y * cv.y;
        }
        sc = wred(sc);
        if (lane == 0) m.Ssum[d] = sc;
    }
    __syncthreads();

    if (tid == 0) {
        int best = 0; float bv = m.Ssum[0];
        for (int i = 1; i < 16; ++i)
            if (m.Ssum[i] > bv) { bv = m.Ssum[i]; best = i; }   // first-max
        m.sel = best;
    }
    __syncthreads();

    if (tid < OFC) {
        float a = 0.f;
        #pragma unroll 3
        for (int t = 0; t < TDN; ++t) a += m.attn[m.sel][t] * st.vpp[t][tid];
        m.avsel[tid] = a;
    }
    __syncthreads();

    if (tid < OFC) {                                   // arow stays in LDS
        const float2* a  = (const float2*)&m.avsel[0];
        const float2* w2 = (const float2*)&m.u1.ph.owpad[tid][0];
        float a0 = 0.f;
        #pragma unroll 4
        for (int j = 0; j < 59; ++j) {
            float2 u = a[j], v = w2[j];
            a0 += u.x * v.x + u.y * v.y;
        }
        P.arow[tid] = a0 + P.bout[tid];
    }
    __syncthreads();                                   // phase2 state now dead

    // ================= inline branches =================
    BrScratch& br = m.u1.br;                           // aliases dead owpad

    // --- kv-r1 branch ---
    if (tid < OFC) {
        const float aj = P.a_[tid];
        float mx = -INFINITY;
        for (int t = 0; t < OFC; ++t) mx = fmaxf(mx, aj * P.arow[t]);
        float l = 0.f, d = 0.f;
        for (int t = 0; t < OFC; ++t) {
            float e = __expf(aj * P.arow[t] - mx);
            l += e;
            d += e * P.arow[t];
        }
        br.dvec[tid] = d / l;
    }
    __syncthreads();
    if (tid < COUT * 22) {
        int c = tid / 22, grp = tid - (tid / 22) * 22;
        int pbase = grp * 5;
        float win[13];
        #pragma unroll
        for (int t = 0; t < 13; ++t) win[t] = br.dvec[pbase + t];
        float acc5[5];
        #pragma unroll
        for (int i = 0; i < 5; ++i) acc5[i] = P.cb2[c];
        #pragma unroll
        for (int k = 0; k < KS; ++k) {
            float wv = P.Gc[c][k];
            #pragma unroll
            for (int i = 0; i < 5; ++i) acc5[i] += win[i + k] * wv;
        }
        float mx = fmaxf(fmaxf(fmaxf(acc5[0], acc5[1]), fmaxf(acc5[2], acc5[3])), acc5[4]);
        br.y[c][grp] = fmaxf(mx, 0.f);
    }
    __syncthreads();
    if (tid < COUT) {
        float mx = br.y[tid][0];
        for (int g2 = 1; g2 < 22; ++g2) mx = fmaxf(mx, br.y[tid][g2]);
        P.feats[kr * COUT + tid] = mx;
    }
    __syncthreads();

    // --- d_r1 branch: flash attention over eeg kv ---
    {
        const int g = tid >> 7, j = tid & 127;
        float acc[16];
        float mm = -INFINITY, l = 0.f;
        #pragma unroll
        for (int r = 0; r < 16; ++r) acc[r] = 0.f;
        if (j < OFC) {
            const float aj = P.arow[j];
            const int t0 = (g * OFC) >> 2, t1 = ((g + 1) * OFC) >> 2;
            for (int t = t0; t < t1; ++t) {
                float sc = 0.25f * fmaf(aj, P.u[t], P.v2[t]);
                float mn = fmaxf(mm, sc);
                float c  = __expf(mm - mn);
                float pp = __expf(sc - mn);
                l = l * c + pp;
                const float* vr = &P.vpS[t][0];
                #pragma unroll
                for (int r = 0; r < 16; ++r) acc[r] = acc[r] * c + pp * vr[r];
                mm = mn;
            }
            br.part_m[g][j] = mm;
            br.part_l[g][j] = l;
            #pragma unroll
            for (int r = 0; r < 16; ++r) br.part_acc[g][j][r] = acc[r];
        }
    }
    __syncthreads();
    if (tid < OFC) {
        float m0 = br.part_m[0][tid], m1 = br.part_m[1][tid];
        float m2 = br.part_m[2][tid], m3 = br.part_m[3][tid];
        float mx = fmaxf(fmaxf(m0, m1), fmaxf(m2, m3));
        float c0 = __expf(m0 - mx), c1 = __expf(m1 - mx);
        float c2 = __expf(m2 - mx), c3 = __expf(m3 - mx);
        float ll = c0 * br.part_l[0][tid] + c1 * br.part_l[1][tid]
                 + c2 * br.part_l[2][tid] + c3 * br.part_l[3][tid];
        float inv = 1.f / ll;
        float orow[16];
        #pragma unroll
        for (int r = 0; r < 16; ++r)
            orow[r] = (c0 * br.part_acc[0][tid][r] + c1 * br.part_acc[1][tid][r]
                     + c2 * br.part_acc[2][tid][r] + c3 * br.part_acc[3][tid][r]) * inv;
        for (int c = 0; c < 16; ++c) {
            float a = P.b_out_dr[c];
            #pragma unroll
            for (int d = 0; d < 16; ++d) a += orow[d] * P.w_out_dr[c][d];
            br.o2[tid][c] = a;
        }
    }
    __syncthreads();
    if (tid < COUT * 22) {
        int c = tid / 22, grp = tid - (tid / 22) * 22;
        int pbase = grp * 5;
        float acc5[5];
        #pragma unroll
        for (int i = 0; i < 5; ++i) acc5[i] = P.cb_dr[c];
        for (int mI = 0; mI < 16; ++mI) {
            float win[13];
            #pragma unroll
            for (int t = 0; t < 13; ++t) win[t] = br.o2[pbase + t][mI];
            #pragma unroll
            for (int k = 0; k < KS; ++k) {
                float wv = P.cw_dr[(c * 16 + mI) * KS + k];
                #pragma unroll
                for (int i = 0; i < 5; ++i) acc5[i] += win[i + k] * wv;
            }
        }
        float mx = fmaxf(fmaxf(fmaxf(acc5[0], acc5[1]), fmaxf(acc5[2], acc5[3])), acc5[4]);
        br.y[c][grp] = fmaxf(mx, 0.f);
    }
    __syncthreads();
    if (tid < COUT) {
        float mx = br.y[tid][0];
        for (int g2 = 1; g2 < 22; ++g2) mx = fmaxf(mx, br.y[tid][g2]);
        P.feats[dr * COUT + tid] = mx;
    }

    // ================= feats exchange + head =================
    if (b == 1) {
        __syncthreads();
        if (tid < 20) p.ws[WS_FEATS + 20 + tid] = P.feats[20 + tid];
        postM(&flags[28 * 16], tid);
    } else {
        waitM(flags, 28, 1, tid);
        if (tid < NSLOTS)
            __hip_atomic_store(&flags[tid * 16], 0,
                               __ATOMIC_RELAXED, __HIP_MEMORY_SCOPE_AGENT);
        if (tid < 20) P.feats[20 + tid] = p.ws[WS_FEATS + 20 + tid];
        __syncthreads();
        if (tid < 40) {
            float a = P.fc1b[tid];
            for (int k = 0; k < 40; ++k) a += P.feats[k] * P.fc1w[tid * 40 + k];
            P.hh[tid] = 1.f / (1.f + __expf(-a));
        }
        __syncthreads();
        if (tid < 2) {
            float a = P.fc2b[tid];
            for (int k = 0; k < 40; ++k) a += P.hh[k] * P.fc2w[tid * 40 + k];
            p.out[tid] = 1.f / (1.f + __expf(-a));
        }
    }
}

// ---------------------------------------------------------------------------
__global__ __launch_bounds__(512) void fused_net(Params p)
{
    __shared__ Sm sm;
    const int blk = blockIdx.x;
    const int tid = threadIdx.x;
    int* flags = (int*)(p.ws + WS_FLAGS);

    if (blk >= 2) {
        // q/k/v projections: blocks 2..15 side A, 16..29 side B (14 each)
        const int side = (blk < 16) ? 0 : 1;
        const int gw   = (blk - (side ? 16 : 2)) * 8 + (tid >> 6);
        if (gw < 110) proj_task(side, gw, tid & 63, p);
        postM(&flags[(blk - 2) * 16], tid);
        return;
    }
    main_block(blk, tid, p, sm);
}

// ---------------------------------------------------------------------------
extern "C" void kernel_launch(void* const* d_in, const int* in_sizes, int n_in,
                              void* d_out, int out_size, void* d_ws, size_t ws_size,
                              hipStream_t stream) {
    Params prm;
    prm.x         = (const float*)d_in[0];
    prm.tdA_in_w  = (const float*)d_in[1];
    prm.tdA_in_b  = (const float*)d_in[2];
    prm.tdA_out_w = (const float*)d_in[3];
    prm.tdA_out_b = (const float*)d_in[4];
    prm.tdB_in_w  = (const float*)d_in[5];
    prm.tdB_in_b  = (const float*)d_in[6];
    prm.tdB_out_w = (const float*)d_in[7];
    prm.tdB_out_b = (const float*)d_in[8];
    prm.cm_in_w   = (const float*)d_in[9];
    prm.cm_in_b   = (const float*)d_in[10];
    prm.cm_out_w  = (const float*)d_in[11];
    prm.cm_out_b  = (const float*)d_in[12];
    prm.projA_w   = (const float*)d_in[13];
    prm.projB_w   = (const float*)d_in[14];
    prm.conv_w    = (const float*)d_in[15];
    prm.conv_b    = (const float*)d_in[16];
    prm.fc1_w     = (const float*)d_in[17];
    prm.fc1_b     = (const float*)d_in[18];
    prm.fc2_w     = (const float*)d_in[19];
    prm.fc2_b     = (const float*)d_in[20];
    prm.ws        = (float*)d_ws;
    prm.out       = (float*)d_out;

    fused_net<<<dim3(30), dim3(512), 0, stream>>>(prm);
}

// Round 12
// 39.699 us; speedup vs baseline: 1.8007x; 1.1652x over previous
//
#include <hip/hip_runtime.h>
#include <math.h>

#define WL   140
#define OFC  118
#define TDN  21
#define COUT 10
#define KS   9
#define IW_SZ (OFC * OFC)       // 13924

// ws layout (floats)
#define PROJ_STRIDE 6848
#define KP_OFF      1888
#define VP_OFF      4368
#define WS_ATT_A    13696
#define WS_ATT_B    13824
#define WS_FEATS    13952
#define WS_FLAGS    14080        // int slots from here (self-resetting protocol)

// flag slots (stride 16 ints): proj blocks 2..29 -> slot blk-2 (0..27);
// attA=28, attB=29; feats br -> 30+br (30..33). 34 slots.
#define MAGIC 0x1F2E3D4C
#define NSLOTS 34

struct Params {
    const float *x;
    const float *tdA_in_w, *tdA_in_b, *tdA_out_w, *tdA_out_b;
    const float *tdB_in_w, *tdB_in_b, *tdB_out_w, *tdB_out_b;
    const float *cm_in_w, *cm_in_b, *cm_out_w, *cm_out_b;
    const float *projA_w, *projB_w, *conv_w, *conv_b;
    const float *fc1_w, *fc1_b, *fc2_w, *fc2_b;
    float *fc_unused;
    float *ws, *out;
};

struct TdSm {                     // blocks 0,1 (phase 2 owners)
    float owpad[OFC][122];        // out_w, padded rows
    float qpp[16][122];
    float kpp[TDN][122];
    float vpp[TDN][122];
    float attn[16][22];
    float acs[22];
    float avcs[120];
    float colsum[120];
    float Ssum[16];
    float avsel[120];
    int   sel;
};

struct BrSm {                     // blocks 30..33
    float arow[120];
    float pv[16];
    float eeg_s[16][OFC];
    float w_inT[16][48];
    float b_in[48];
    float tv[3][16];
    float w_out[16][16];
    float b_out[16];
    float cw[COUT * 16 * KS];
    float cb[COUT];
    // br0/br3 (q rank-1):
    float kpS[OFC][17];
    float vpS[OFC][17];
    float u[120], v2[120];
    float part_m[4][128];
    float part_l[4][128];
    float part_acc[4][OFC][17];
    float o2[OFC][17];
    // br1/br2 (kv rank-1):
    float qpS[OFC][17];
    float a_[120], dvec[120];
    float Avec[16], Bvec[16];
    float Gc[COUT][KS], cb2[COUT];
    float y[COUT][22];
};

struct HdSm { float f[64]; float h[64]; };

union alignas(16) Sm { TdSm t; BrSm b; HdSm h; };

__device__ inline float wred(float v) {
    #pragma unroll
    for (int off = 32; off; off >>= 1) v += __shfl_xor(v, off);
    return v;
}

// producer: barrier (all block stores done) + single RELEASE store of MAGIC
__device__ inline void postM(int* f, int tid) {
    __syncthreads();
    if (tid == 0)
        __hip_atomic_store(f, MAGIC, __ATOMIC_RELEASE, __HIP_MEMORY_SCOPE_AGENT);
}

// consumer: relaxed spin on n slots; ONE acquire fence when all are MAGIC
__device__ inline void waitM(int* base, int first, int n, int tid) {
    if (tid == 0) {
        for (int i = 0; i < n; ++i) {
            int* f = base + (first + i) * 16;
            while (__hip_atomic_load(f, __ATOMIC_RELAXED, __HIP_MEMORY_SCOPE_AGENT) != MAGIC)
                __builtin_amdgcn_s_sleep(1);
        }
        __builtin_amdgcn_fence(__ATOMIC_ACQUIRE, "agent");
    }
    __syncthreads();
}

// ---------------------------------------------------------------------------
// Direct-global td projection. One wave handles ALL rows x a few o-columns:
//  q  (sec 0): lane = r*4 + oi  (16 r x 4 o), 30 waves/side
//  k,v(sec1,2): lane = r*3 + oi (21 r x 3 o), 40 waves/side each
// Lanes sharing o read the SAME contiguous W[o][j] (merged by the TA);
// k/v input reads are lane-contiguous (overlapping windows). No LDS.
// ---------------------------------------------------------------------------
__device__ void td_proj_direct(int side, int lw, int lane, const Params& p)
{
    int sec, o, r, R;
    if (lw < 30) {
        sec = 0; o = lw * 4 + (lane & 3); r = lane >> 2; R = 16;
    } else {
        sec = (lw < 70) ? 1 : 2;
        int base = (lw - (sec == 1 ? 30 : 70)) * 3;
        o = base + lane % 3; r = lane / 3; R = TDN;
    }
    if (o >= OFC || r >= R) return;

    const float* in_w = (side ? p.tdB_in_w : p.tdA_in_w) + sec * IW_SZ + o * OFC;
    const float  bias = (side ? p.tdB_in_b : p.tdA_in_b)[sec * OFC + o];
    const float2* w2  = (const float2*)in_w;          // o*118 even -> 8B aligned
    float s0 = 0.f;

    if (sec == 0) {
        const float2* a = (const float2*)(p.x + (1 + r) * WL + (WL - OFC));
        #pragma unroll 4
        for (int j = 0; j < 59; ++j) {
            float2 u = a[j], w = w2[j];
            s0 += u.x * w.x + u.y * w.y;
        }
        s0 = (s0 + bias) * (1.0f / sqrtf(118.0f));
    } else {
        const float* wr = p.x + (side ? 17 * WL : 0) + r;
        #pragma unroll 4
        for (int j = 0; j < 59; ++j) {
            float2 w = w2[j];
            s0 += wr[2 * j] * w.x + wr[2 * j + 1] * w.y;
        }
        s0 += bias;
    }
    p.ws[side * PROJ_STRIDE
         + (sec == 0 ? 0 : (sec == 1 ? KP_OFF : VP_OFF))
         + r * OFC + o] = s0;
}

// ---------------------------------------------------------------------------
// phase 2 (blocks 0,1): scores + softmax + colsum row-select + selected row.
// ---------------------------------------------------------------------------
__device__ void td_phase2(int b, int tid, const Params& p, TdSm& s)
{
    const float* base  = p.ws + b * PROJ_STRIDE;
    const float* out_b = b ? p.tdB_out_b : p.tdA_out_b;
    const int wid = tid >> 6, lane = tid & 63;

    for (int e = tid; e < 16 * 59; e += 512) {
        int r = e / 59, j = e - r * 59;
        ((float2*)&s.qpp[r][0])[j] = ((const float2*)(base + r * OFC))[j];
    }
    for (int e = tid; e < TDN * 59; e += 512) {
        int t = e / 59, j = e - t * 59;
        ((float2*)&s.kpp[t][0])[j] = ((const float2*)(base + KP_OFF + t * OFC))[j];
        ((float2*)&s.vpp[t][0])[j] = ((const float2*)(base + VP_OFF + t * OFC))[j];
    }
    __syncthreads();

    if (tid < 16 * TDN) {
        int i = tid / TDN, t = tid - (tid / TDN) * TDN;
        const float2* q = (const float2*)&s.qpp[i][0];
        const float2* k = (const float2*)&s.kpp[t][0];
        float sc = 0.f;
        #pragma unroll 4
        for (int j = 0; j < 59; ++j) {
            float2 u = q[j], v = k[j];
            sc += u.x * v.x + u.y * v.y;
        }
        s.attn[i][t] = sc;
    }
    __syncthreads();

    if (tid < 16) {
        float m = s.attn[tid][0];
        for (int t = 1; t < TDN; ++t) m = fmaxf(m, s.attn[tid][t]);
        float l = 0.f;
        for (int t = 0; t < TDN; ++t) {
            float pp = __expf(s.attn[tid][t] - m);
            s.attn[tid][t] = pp;
            l += pp;
        }
        float inv = 1.f / l;
        for (int t = 0; t < TDN; ++t) s.attn[tid][t] *= inv;
    }
    __syncthreads();

    if (tid < TDN) {
        float a = 0.f;
        for (int i = 0; i < 16; ++i) a += s.attn[i][tid];
        s.acs[tid] = a;
    }
    __syncthreads();

    if (tid < OFC) {
        float a = 0.f;
        for (int t = 0; t < TDN; ++t) a += s.acs[t] * s.vpp[t][tid];
        s.avcs[tid] = a;
    }
    __syncthreads();

    if (tid < OFC) {
        const float2* a  = (const float2*)&s.avcs[0];
        const float2* w2 = (const float2*)&s.owpad[tid][0];
        float a0 = 0.f;
        #pragma unroll 4
        for (int j = 0; j < 59; ++j) {
            float2 u = a[j], v = w2[j];
            a0 += u.x * v.x + u.y * v.y;
        }
        s.colsum[tid] = a0 + 16.f * out_b[tid];
    }
    __syncthreads();

    for (int d = wid; d < 16; d += 8) {
        const float* er = p.x + (1 + d) * WL + (WL - OFC);
        int j0 = lane * 2;
        float sc = 0.f;
        if (j0 < OFC) {
            float2 ev = *(const float2*)(er + j0);
            float2 cv = *(const float2*)(&s.colsum[j0]);
            sc = ev.x * cv.x + ev.y * cv.y;
        }
        sc = wred(sc);
        if (lane == 0) s.Ssum[d] = sc;
    }
    __syncthreads();

    if (tid == 0) {
        int best = 0; float bv = s.Ssum[0];
        for (int i = 1; i < 16; ++i)
            if (s.Ssum[i] > bv) { bv = s.Ssum[i]; best = i; }   // first-max
        s.sel = best;
    }
    __syncthreads();

    if (tid < OFC) {
        float a = 0.f;
        for (int t = 0; t < TDN; ++t) a += s.attn[s.sel][t] * s.vpp[t][tid];
        s.avsel[tid] = a;
    }
    __syncthreads();

    if (tid < OFC) {
        const float2* a  = (const float2*)&s.avsel[0];
        const float2* w2 = (const float2*)&s.owpad[tid][0];
        float a0 = 0.f;
        #pragma unroll 4
        for (int j = 0; j < 59; ++j) {
            float2 u = a[j], v = w2[j];
            a0 += u.x * v.x + u.y * v.y;
        }
        p.ws[(b ? WS_ATT_B : WS_ATT_A) + tid] = a0 + out_b[tid];
    }
}

// ---------------------------------------------------------------------------
// branch prestage (blocks 30..33): everything that doesn't need arow.
// ---------------------------------------------------------------------------
__device__ void br_pre(int br, int tid, const Params& p, BrSm& s)
{
    const bool d_r1 = (br == 0 || br == 3);   // q side rank-1 (data = wA/wB)

    for (int e = tid; e < 16 * OFC; e += 512) {
        int r = e / OFC, c = e - (e / OFC) * OFC;
        s.eeg_s[r][c] = p.x[(1 + r) * WL + (WL - OFC) + c];
    }
    for (int e = tid; e < 768; e += 512) {
        int q = e / 16, r = e % 16;
        s.w_inT[r][q] = p.cm_in_w[br * 768 + e];
    }
    if (tid < 48) s.b_in[tid] = p.cm_in_b[br * 48 + tid];
    if (tid >= 64 && tid < 320) {
        int e = tid - 64;
        s.w_out[e >> 4][e & 15] = p.cm_out_w[br * 256 + e];
    }
    if (tid >= 384 && tid < 400) s.b_out[tid - 384] = p.cm_out_b[br * 16 + (tid - 384)];
    for (int e = tid; e < COUT * 16 * KS; e += 512) s.cw[e] = p.conv_w[br * 1440 + e];
    if (tid >= 400 && tid < 410) s.cb[tid - 400] = p.conv_b[br * COUT + (tid - 400)];
    {
        const float* pvg = (br < 2) ? p.projA_w : p.projB_w;
        if (tid >= 416 && tid < 432) s.pv[tid - 416] = pvg[tid - 416];
    }
    __syncthreads();

    if (tid < 48) {
        float a = 0.f;
        #pragma unroll
        for (int r = 0; r < 16; ++r) a += s.pv[r] * s.w_inT[r][tid];
        s.tv[tid / 16][tid % 16] = a;
    }
    __syncthreads();

    if (d_r1) {
        for (int e = tid; e < 2 * OFC * 16; e += 512) {
            int sec01 = e / (OFC * 16);
            int rem = e - sec01 * OFC * 16;
            int j = rem >> 4, o = rem & 15;
            float a = 0.f;
            #pragma unroll
            for (int r = 0; r < 16; ++r) a += s.eeg_s[r][j] * s.w_inT[r][(1 + sec01) * 16 + o];
            a += s.b_in[(1 + sec01) * 16 + o];
            (sec01 ? &s.vpS[0][0] : &s.kpS[0][0])[j * 17 + o] = a;
        }
        __syncthreads();
        if (tid < OFC) {
            float uu = 0.f, vv = 0.f;
            #pragma unroll
            for (int o = 0; o < 16; ++o) {
                float kv = s.kpS[tid][o];
                uu += s.tv[0][o] * kv;
                vv += s.b_in[o] * kv;
            }
            s.u[tid] = uu; s.v2[tid] = vv;
        }
    } else {
        for (int e = tid; e < OFC * 16; e += 512) {
            int j = e >> 4, o = e & 15;
            float a = 0.f;
            #pragma unroll
            for (int r = 0; r < 16; ++r) a += s.eeg_s[r][j] * s.w_inT[r][o];
            s.qpS[j][o] = (a + s.b_in[o]) * 0.25f;
        }
        __syncthreads();
        if (tid < OFC) {
            float a = 0.f;
            #pragma unroll
            for (int o = 0; o < 16; ++o) a += s.qpS[tid][o] * s.tv[1][o];
            s.a_[tid] = a;
        }
        if (tid >= 128 && tid < 144) {
            int c = tid - 128;
            float A = 0.f, B = 0.f;
            #pragma unroll
            for (int o = 0; o < 16; ++o) {
                A += s.tv[2][o] * s.w_out[c][o];
                B += s.b_in[32 + o] * s.w_out[c][o];
            }
            s.Avec[c] = A;
            s.Bvec[c] = B + s.b_out[c];
        }
        __syncthreads();
        if (tid < COUT * KS) {
            int c = tid / KS, k = tid - (tid / KS) * KS;
            float g = 0.f;
            #pragma unroll
            for (int m = 0; m < 16; ++m) g += s.Avec[m] * s.cw[(c * 16 + m) * KS + k];
            s.Gc[c][k] = g;
        }
        if (tid >= 128 && tid < 128 + COUT) {
            int c = tid - 128;
            float cc = s.cb[c];
            #pragma unroll
            for (int m = 0; m < 16; ++m) {
                float bsum = 0.f;
                #pragma unroll
                for (int k = 0; k < KS; ++k) bsum += s.cw[(c * 16 + m) * KS + k];
                cc += s.Bvec[m] * bsum;
            }
            s.cb2[c] = cc;
        }
    }
}

// ---------------------------------------------------------------------------
// branch main (blocks 30..33), after arow is available.
// ---------------------------------------------------------------------------
__device__ void br_main(int br, int tid, const Params& p, BrSm& s)
{
    const bool d_r1 = (br == 0 || br == 3);
    const float* ar = p.ws + ((br < 2) ? WS_ATT_A : WS_ATT_B);
    if (tid < OFC) s.arow[tid] = ar[tid];
    __syncthreads();

    if (d_r1) {
        const int g = tid >> 7, j = tid & 127;
        float acc[16];
        float m = -INFINITY, l = 0.f;
        #pragma unroll
        for (int r = 0; r < 16; ++r) acc[r] = 0.f;

        if (j < OFC) {
            const float aj = s.arow[j];
            const int t0 = (g * OFC) >> 2, t1 = ((g + 1) * OFC) >> 2;
            for (int t = t0; t < t1; ++t) {
                float sc = 0.25f * fmaf(aj, s.u[t], s.v2[t]);
                float mn = fmaxf(m, sc);
                float c  = __expf(m - mn);
                float pp = __expf(sc - mn);
                l = l * c + pp;
                const float* vr = &s.vpS[t][0];
                #pragma unroll
                for (int r = 0; r < 16; ++r) acc[r] = acc[r] * c + pp * vr[r];
                m = mn;
            }
            s.part_m[g][j] = m;
            s.part_l[g][j] = l;
            #pragma unroll
            for (int r = 0; r < 16; ++r) s.part_acc[g][j][r] = acc[r];
        }
        __syncthreads();

        if (tid < OFC) {
            float m0 = s.part_m[0][tid], m1 = s.part_m[1][tid];
            float m2 = s.part_m[2][tid], m3 = s.part_m[3][tid];
            float mm = fmaxf(fmaxf(m0, m1), fmaxf(m2, m3));
            float c0 = __expf(m0 - mm), c1 = __expf(m1 - mm);
            float c2 = __expf(m2 - mm), c3 = __expf(m3 - mm);
            float ll = c0 * s.part_l[0][tid] + c1 * s.part_l[1][tid]
                     + c2 * s.part_l[2][tid] + c3 * s.part_l[3][tid];
            float inv = 1.f / ll;
            float orow[16];
            #pragma unroll
            for (int r = 0; r < 16; ++r)
                orow[r] = (c0 * s.part_acc[0][tid][r] + c1 * s.part_acc[1][tid][r]
                         + c2 * s.part_acc[2][tid][r] + c3 * s.part_acc[3][tid][r]) * inv;
            for (int c = 0; c < 16; ++c) {
                float a = s.b_out[c];
                #pragma unroll
                for (int d = 0; d < 16; ++d) a += orow[d] * s.w_out[c][d];
                s.o2[tid][c] = a;
            }
        }
        __syncthreads();

        if (tid < COUT * 22) {
            int c = tid / 22, grp = tid - (tid / 22) * 22;
            int pbase = grp * 5;
            float acc5[5];
            #pragma unroll
            for (int i = 0; i < 5; ++i) acc5[i] = s.cb[c];
            for (int mI = 0; mI < 16; ++mI) {
                float win[13];
                #pragma unroll
                for (int t = 0; t < 13; ++t) win[t] = s.o2[pbase + t][mI];
                #pragma unroll
                for (int k = 0; k < KS; ++k) {
                    float wv = s.cw[(c * 16 + mI) * KS + k];
                    #pragma unroll
                    for (int i = 0; i < 5; ++i) acc5[i] += win[i + k] * wv;
                }
            }
            float mx = fmaxf(fmaxf(fmaxf(acc5[0], acc5[1]), fmaxf(acc5[2], acc5[3])), acc5[4]);
            s.y[c][grp] = fmaxf(mx, 0.f);
        }
        __syncthreads();
    } else {
        if (tid < OFC) {
            const float aj = s.a_[tid];
            float m = -INFINITY;
            for (int t = 0; t < OFC; ++t) m = fmaxf(m, aj * s.arow[t]);
            float l = 0.f, d = 0.f;
            for (int t = 0; t < OFC; ++t) {
                float e = __expf(aj * s.arow[t] - m);
                l += e;
                d += e * s.arow[t];
            }
            s.dvec[tid] = d / l;
        }
        __syncthreads();

        if (tid < COUT * 22) {
            int c = tid / 22, grp = tid - (tid / 22) * 22;
            int pbase = grp * 5;
            float win[13];
            #pragma unroll
            for (int t = 0; t < 13; ++t) win[t] = s.dvec[pbase + t];
            float acc5[5];
            #pragma unroll
            for (int i = 0; i < 5; ++i) acc5[i] = s.cb2[c];
            #pragma unroll
            for (int k = 0; k < KS; ++k) {
                float wv = s.Gc[c][k];
                #pragma unroll
                for (int i = 0; i < 5; ++i) acc5[i] += win[i + k] * wv;
            }
            float mx = fmaxf(fmaxf(fmaxf(acc5[0], acc5[1]), fmaxf(acc5[2], acc5[3])), acc5[4]);
            s.y[c][grp] = fmaxf(mx, 0.f);
        }
        __syncthreads();
    }

    if (tid < COUT) {
        float mx = s.y[tid][0];
        for (int g2 = 1; g2 < 22; ++g2) mx = fmaxf(mx, s.y[tid][g2]);
        p.ws[WS_FEATS + br * COUT + tid] = mx;
    }
}

// ---------------------------------------------------------------------------
__global__ __launch_bounds__(512) void fused_net(Params p)
{
    __shared__ Sm sm;
    const int blk = blockIdx.x;
    const int tid = threadIdx.x;
    int* flags = (int*)(p.ws + WS_FLAGS);

    if (blk >= 2 && blk < 30) {
        // direct-global projections: blocks 2..15 side A, 16..29 side B
        const int side = (blk < 16) ? 0 : 1;
        const int gw   = (blk - (side ? 16 : 2)) * 8 + (tid >> 6);
        if (gw < 110) td_proj_direct(side, gw, tid & 63, p);
        postM(&flags[(blk - 2) * 16], tid);
        return;
    }

    if (blk < 2) {
        // stage out_w (padded) while proj blocks run
        const float* ow = blk ? p.tdB_out_w : p.tdA_out_w;
        for (int e = tid; e < OFC * 59; e += 512) {
            int o = e / 59, j = e - o * 59;
            ((float2*)&sm.t.owpad[o][0])[j] = ((const float2*)(ow + o * OFC))[j];
        }
        waitM(flags, blk ? 14 : 0, 14, tid);            // own side's 14 proj slots
        td_phase2(blk, tid, p, sm.t);
        postM(&flags[(28 + blk) * 16], tid);            // attA / attB

        if (blk == 0) {
            waitM(flags, 30, 4, tid);                   // 4 feats slots
            // reset all slots for the next replay (safe: every flag read in
            // the system happens-before feats==MAGIC observed here)
            if (tid < NSLOTS)
                __hip_atomic_store(&flags[tid * 16], 0,
                                   __ATOMIC_RELAXED, __HIP_MEMORY_SCOPE_AGENT);
            __syncthreads();
            if (tid < 40) sm.h.f[tid] = p.ws[WS_FEATS + tid];
            __syncthreads();
            if (tid < 40) {
                float a = p.fc1_b[tid];
                for (int k = 0; k < 40; ++k) a += sm.h.f[k] * p.fc1_w[tid * 40 + k];
                sm.h.h[tid] = 1.f / (1.f + __expf(-a));
            }
            __syncthreads();
            if (tid < 2) {
                float a = p.fc2_b[tid];
                for (int k = 0; k < 40; ++k) a += sm.h.h[k] * p.fc2_w[tid * 40 + k];
                p.out[tid] = 1.f / (1.f + __expf(-a));
            }
        }
        return;
    }

    // blocks 30..33: branches
    const int br = blk - 30;
    br_pre(br, tid, p, sm.b);
    waitM(flags, (br < 2) ? 28 : 29, 1, tid);           // attA or attB
    br_main(br, tid, p, sm.b);
    postM(&flags[(30 + br) * 16], tid);
}

// ---------------------------------------------------------------------------
extern "C" void kernel_launch(void* const* d_in, const int* in_sizes, int n_in,
                              void* d_out, int out_size, void* d_ws, size_t ws_size,
                              hipStream_t stream) {
    Params prm;
    prm.x         = (const float*)d_in[0];
    prm.tdA_in_w  = (const float*)d_in[1];
    prm.tdA_in_b  = (const float*)d_in[2];
    prm.tdA_out_w = (const float*)d_in[3];
    prm.tdA_out_b = (const float*)d_in[4];
    prm.tdB_in_w  = (const float*)d_in[5];
    prm.tdB_in_b  = (const float*)d_in[6];
    prm.tdB_out_w = (const float*)d_in[7];
    prm.tdB_out_b = (const float*)d_in[8];
    prm.cm_in_w   = (const float*)d_in[9];
    prm.cm_in_b   = (const float*)d_in[10];
    prm.cm_out_w  = (const float*)d_in[11];
    prm.cm_out_b  = (const float*)d_in[12];
    prm.projA_w   = (const float*)d_in[13];
    prm.projB_w   = (const float*)d_in[14];
    prm.conv_w    = (const float*)d_in[15];
    prm.conv_b    = (const float*)d_in[16];
    prm.fc1_w     = (const float*)d_in[17];
    prm.fc1_b     = (const float*)d_in[18];
    prm.fc2_w     = (const float*)d_in[19];
    prm.fc2_b     = (const float*)d_in[20];
    prm.fc_unused = nullptr;
    prm.ws        = (float*)d_ws;
    prm.out       = (float*)d_out;

    fused_net<<<dim3(34), dim3(512), 0, stream>>>(prm);
}